// Round 6
// baseline (59.265 us; speedup 1.0000x reference)
//
#include <hip/hip_runtime.h>
#include <hip/hip_bf16.h>

#define BATCH 16
#define CHAN  256
#define HW    16384
#define NCLS  6

typedef float  f32x4 __attribute__((ext_vector_type(4)));
typedef int    i32x4 __attribute__((ext_vector_type(4)));

// Kernel A: compress int32 labels (values 0..5, 255) to u8 in d_ws.
// 262144 labels total; 256 blocks x 256 threads x 4 labels.
__global__ __launch_bounds__(256)
void compress_kernel(const int* __restrict__ gt, unsigned char* __restrict__ g8) {
    const int idx = (blockIdx.x * 256 + threadIdx.x) * 4;
    const i32x4 L = *reinterpret_cast<const i32x4*>(gt + idx);
    unsigned int packed = (unsigned int)(L.x & 0xff)
                        | ((unsigned int)(L.y & 0xff) << 8)
                        | ((unsigned int)(L.z & 0xff) << 16)
                        | ((unsigned int)(L.w & 0xff) << 24);
    *reinterpret_cast<unsigned int*>(g8 + idx) = packed;
}

// Kernel B: one block per (b,c). 256 threads, 64 px/thread, 16 fully
// unrolled iterations of {float4 x-load + 1-dword u8-label load}.
// Full unroll keeps ~32 loads in flight per wave; u8 labels cut 48 VGPRs
// vs int32 labels -> 4 blocks/CU instead of 2.
__global__ __launch_bounds__(256, 4)
void gt2center_kernel(const float* __restrict__ x,
                      const unsigned char* __restrict__ g8,
                      float* __restrict__ out) {
    const int bc = blockIdx.x;          // b*CHAN + c
    const int b  = bc >> 8;             // CHAN == 256
    const int c  = bc & 255;
    const float* __restrict__ xp = x  + (size_t)bc * HW;
    const unsigned char* __restrict__ gp = g8 + (size_t)b * HW;
    const int t = threadIdx.x;

    float s[NCLS];
    int   cnt[NCLS];
#pragma unroll
    for (int k = 0; k < NCLS; ++k) { s[k] = 0.0f; cnt[k] = 0; }

#pragma unroll
    for (int i = 0; i < 16; ++i) {
        const int n = i * 1024 + t * 4;
        const f32x4 v = *reinterpret_cast<const f32x4*>(xp + n);
        const unsigned int Lw = *reinterpret_cast<const unsigned int*>(gp + n);
        const int l0 = Lw & 0xff;
        const int l1 = (Lw >> 8) & 0xff;
        const int l2 = (Lw >> 16) & 0xff;
        const int l3 = Lw >> 24;
#pragma unroll
        for (int k = 0; k < NCLS; ++k) {
            s[k] += (l0 == k) ? v.x : 0.0f;
            s[k] += (l1 == k) ? v.y : 0.0f;
            s[k] += (l2 == k) ? v.z : 0.0f;
            s[k] += (l3 == k) ? v.w : 0.0f;
            cnt[k] += (l0 == k) + (l1 == k) + (l2 == k) + (l3 == k);
        }
    }

    // 64-lane butterfly reduce
#pragma unroll
    for (int off = 32; off >= 1; off >>= 1) {
#pragma unroll
        for (int k = 0; k < NCLS; ++k) {
            s[k]   += __shfl_xor(s[k],   off, 64);
            cnt[k] += __shfl_xor(cnt[k], off, 64);
        }
    }

    __shared__ float ls[4][NCLS];
    __shared__ int   lc[4][NCLS];
    const int wave = t >> 6, lane = t & 63;
    if (lane == 0) {
#pragma unroll
        for (int k = 0; k < NCLS; ++k) { ls[wave][k] = s[k]; lc[wave][k] = cnt[k]; }
    }
    __syncthreads();

    if (t < NCLS) {
        const float ssum = ls[0][t] + ls[1][t] + ls[2][t] + ls[3][t];
        const int   csum = lc[0][t] + lc[1][t] + lc[2][t] + lc[3][t];
        const float d = (csum > 1) ? (float)csum : 1.0f;
        out[((size_t)b * NCLS + t) * CHAN + c] = ssum / d;
    }
}

extern "C" void kernel_launch(void* const* d_in, const int* in_sizes, int n_in,
                              void* d_out, int out_size, void* d_ws, size_t ws_size,
                              hipStream_t stream) {
    const float* x   = (const float*)d_in[0];
    const int*   gt  = (const int*)d_in[1];
    float*       out = (float*)d_out;
    unsigned char* g8 = (unsigned char*)d_ws;   // BATCH*HW = 256 KiB

    compress_kernel<<<(BATCH * HW) / 1024, 256, 0, stream>>>(gt, g8);
    gt2center_kernel<<<BATCH * CHAN, 256, 0, stream>>>(x, g8, out);
}

// Round 7
// 53.845 us; speedup vs baseline: 1.1007x; 1.1007x over previous
//
#include <hip/hip_runtime.h>
#include <hip/hip_bf16.h>

#define BATCH 16
#define CHAN  256
#define HW    16384
#define NCLS  6

typedef float  f32x4 __attribute__((ext_vector_type(4)));
typedef int    i32x4 __attribute__((ext_vector_type(4)));

// One block per (b,c). 256 threads; 64 pixels/thread, 16 fully-unrolled
// iterations of {nontemporal float4 x-load + cached int4 gt-load}.
// x is a 268MB stream-once: nt bypasses L2/L3 install (and stops it
// evicting the L2-resident gt). Identical to the 49.7us R1 kernel
// except the NT hint on x.
__global__ __launch_bounds__(256)
void gt2center_kernel(const float* __restrict__ x,
                      const int*   __restrict__ gt,
                      float*       __restrict__ out) {
    const int bc = blockIdx.x;          // b*CHAN + c
    const int b  = bc >> 8;             // CHAN == 256
    const int c  = bc & 255;
    const float* __restrict__ xp = x  + (size_t)bc * HW;
    const int*   __restrict__ gp = gt + (size_t)b  * HW;
    const int t = threadIdx.x;

    float s[NCLS];
    int   cnt[NCLS];
#pragma unroll
    for (int k = 0; k < NCLS; ++k) { s[k] = 0.0f; cnt[k] = 0; }

#pragma unroll
    for (int i = 0; i < 16; ++i) {
        const int n = i * 1024 + t * 4;
        const f32x4 v = __builtin_nontemporal_load(
            reinterpret_cast<const f32x4*>(xp + n));
        const i32x4 L = *reinterpret_cast<const i32x4*>(gp + n);
#pragma unroll
        for (int k = 0; k < NCLS; ++k) {
            s[k] += (L.x == k) ? v.x : 0.0f;
            s[k] += (L.y == k) ? v.y : 0.0f;
            s[k] += (L.z == k) ? v.z : 0.0f;
            s[k] += (L.w == k) ? v.w : 0.0f;
            cnt[k] += (L.x == k) + (L.y == k) + (L.z == k) + (L.w == k);
        }
    }

    // 64-lane butterfly reduce
#pragma unroll
    for (int off = 32; off >= 1; off >>= 1) {
#pragma unroll
        for (int k = 0; k < NCLS; ++k) {
            s[k]   += __shfl_xor(s[k],   off, 64);
            cnt[k] += __shfl_xor(cnt[k], off, 64);
        }
    }

    __shared__ float ls[4][NCLS];
    __shared__ int   lc[4][NCLS];
    const int wave = t >> 6, lane = t & 63;
    if (lane == 0) {
#pragma unroll
        for (int k = 0; k < NCLS; ++k) { ls[wave][k] = s[k]; lc[wave][k] = cnt[k]; }
    }
    __syncthreads();

    if (t < NCLS) {
        const float ssum = ls[0][t] + ls[1][t] + ls[2][t] + ls[3][t];
        const int   csum = lc[0][t] + lc[1][t] + lc[2][t] + lc[3][t];
        const float d = (csum > 1) ? (float)csum : 1.0f;
        out[((size_t)b * NCLS + t) * CHAN + c] = ssum / d;
    }
}

extern "C" void kernel_launch(void* const* d_in, const int* in_sizes, int n_in,
                              void* d_out, int out_size, void* d_ws, size_t ws_size,
                              hipStream_t stream) {
    const float* x   = (const float*)d_in[0];
    const int*   gt  = (const int*)d_in[1];
    float*       out = (float*)d_out;
    gt2center_kernel<<<BATCH * CHAN, 256, 0, stream>>>(x, gt, out);
}